// Round 4
// baseline (366.030 us; speedup 1.0000x reference)
//
#include <hip/hip_runtime.h>
#include <stdint.h>

// xxh32 primes
#define XP2 2246822519u
#define XP3 3266489917u
#define XP4 668265263u
#define XP5 374761393u

constexpr int EMB_LEVELS = 1000000;
constexpr int F = 20;
constexpr int UNROLL = 8;
constexpr int BLOCK = 256;

typedef float f32x4 __attribute__((ext_vector_type(4)));

__device__ __forceinline__ uint32_t rotl32(uint32_t v, int r) {
    return (v << r) | (v >> (32 - r));
}

__device__ __forceinline__ uint32_t xxh32_4(uint32_t val, uint32_t seed) {
    uint32_t acc = seed + XP5 + 4u;
    acc += val * XP3;
    acc = rotl32(acc, 17) * XP4;
    acc ^= acc >> 15;
    acc *= XP2;
    acc ^= acc >> 13;
    acc *= XP3;
    acc ^= acc >> 16;
    return acc;
}

// Unit = one float4 of one (n,f) pair's row (16 units/pair, 256B/row).
// Exact-fit tiling: block owns a contiguous 2048-unit chunk; thread does 8
// units at stride 256. Phase 1: all 8 hashes. Phase 2: 8 independent gather
// loads issued back-to-back (max vmcnt MLP). Phase 3: 8 nontemporal stores.
__global__ __launch_bounds__(BLOCK) void ue_kernel(
    const int* __restrict__ x,
    const int* __restrict__ fnum,
    const f32x4* __restrict__ emb,    // [EMB_LEVELS * 16]
    f32x4* __restrict__ out,          // [total_units]
    int total_units)
{
    const int base = blockIdx.x * (BLOCK * UNROLL) + threadIdx.x;

    uint32_t ridx[UNROLL];
    int      lane[UNROLL];
    bool     ok[UNROLL];
    f32x4    v[UNROLL];

    #pragma unroll
    for (int u = 0; u < UNROLL; u++) {
        int t = base + u * BLOCK;
        ok[u] = (t < total_units);
        lane[u] = t & 15;
        int pair = t >> 4;
        int n = pair / F;
        int f = pair - n * F;
        uint32_t val  = ok[u] ? (uint32_t)x[n]    : 0u;
        uint32_t seed = ok[u] ? (uint32_t)fnum[f] : 0u;
        uint32_t h = xxh32_4(val, seed);
        ridx[u] = h % (uint32_t)EMB_LEVELS;
    }

    #pragma unroll
    for (int u = 0; u < UNROLL; u++) {
        if (ok[u]) v[u] = emb[(size_t)ridx[u] * 16 + lane[u]];
    }

    #pragma unroll
    for (int u = 0; u < UNROLL; u++) {
        int t = base + u * BLOCK;
        if (ok[u]) __builtin_nontemporal_store(v[u], &out[(size_t)t]);
    }
}

extern "C" void kernel_launch(void* const* d_in, const int* in_sizes, int n_in,
                              void* d_out, int out_size, void* d_ws, size_t ws_size,
                              hipStream_t stream) {
    const int*   x    = (const int*)d_in[0];     // [N] int32
    const int*   fnum = (const int*)d_in[1];     // [F] int32
    const float* emb  = (const float*)d_in[2];   // [EMB_LEVELS, 64] f32
    float*       out  = (float*)d_out;           // [N, F*64] f32

    int n_rows = in_sizes[0];                    // N = 16384
    int total_pairs = n_rows * F;                // 327,680
    int total_units = total_pairs * 16;          // 5,242,880

    int per_block = BLOCK * UNROLL;              // 2048 units/block
    int grid = (total_units + per_block - 1) / per_block;   // 2560 exact

    ue_kernel<<<grid, BLOCK, 0, stream>>>(
        x, fnum, (const f32x4*)emb, (f32x4*)out, total_units);
}